// Round 1
// baseline (1285.535 us; speedup 1.0000x reference)
//
#include <hip/hip_runtime.h>
#include <hip/hip_bf16.h>
#include <stdint.h>

// GraRPINet: 2-layer GAT. N=40000 nodes, E=640000 edges.
// Pipeline: embed (blockdiag GEMM) -> GAT1(+skip,relu) -> GAT2(+skip) -> out[N,128] f32.
// Edge phase: counting-sort by dst once; per-dst wave softmax + aggregate.
// xs projections stored bf16 (threshold is 2% of max|ref| -- plenty of headroom).

#define HEADS 4
#define CH1   64
#define CH2   32
#define HC1   256   // HEADS*CH1
#define HC2   128   // HEADS*CH2

static constexpr int D_RNA  = 1000;
static constexpr int D_PROT = 300;
static constexpr int D_IN   = 1300;
static constexpr int HDIM   = 128;  // 2H

__device__ __forceinline__ float lrelu(float x) { return x >= 0.f ? x : 0.2f * x; }
__device__ __forceinline__ float bf2f(unsigned int u16) {
  return __uint_as_float(u16 << 16);
}

// ---------------- small utility kernels ----------------
__global__ void zero_i32(int* p, int n) {
  int i = blockIdx.x * 256 + threadIdx.x;
  if (i < n) p[i] = 0;
}

__global__ void hist_kernel(const int* __restrict__ dstv, int* __restrict__ deg, int E) {
  int i = blockIdx.x * 256 + threadIdx.x;
  if (i < E) atomicAdd(&deg[dstv[i]], 1);
}

// single-block scan over N=40000 (40 chunks of 1024, Hillis-Steele per chunk)
__global__ void scan_kernel(const int* __restrict__ deg, int* __restrict__ off,
                            int* __restrict__ cur, int n) {
  __shared__ int s[1024];
  __shared__ int carry_s;
  int tid = threadIdx.x;
  if (tid == 0) carry_s = 0;
  __syncthreads();
  for (int base = 0; base < n; base += 1024) {
    int cbase = carry_s;
    int i = base + tid;
    int v = (i < n) ? deg[i] : 0;
    s[tid] = v;
    __syncthreads();
    for (int o = 1; o < 1024; o <<= 1) {
      int t = (tid >= o) ? s[tid - o] : 0;
      __syncthreads();
      s[tid] += t;
      __syncthreads();
    }
    if (i < n) { int e = cbase + s[tid] - v; off[i] = e; cur[i] = e; }
    __syncthreads();
    if (tid == 1023) carry_s = cbase + s[1023];
    __syncthreads();
  }
  if (tid == 0) off[n] = carry_s;
}

__global__ void scatter_kernel(const int* __restrict__ srcv, const int* __restrict__ dstv,
                               int* __restrict__ cur, int* __restrict__ srcs, int E) {
  int i = blockIdx.x * 256 + threadIdx.x;
  if (i < E) {
    int d = dstv[i];
    int pos = atomicAdd(&cur[d], 1);
    srcs[pos] = srcv[i];
  }
}

// fold att vectors: v[k,h] = sum_c W[k, h*CH+c] * att[h,c]  (so a = h @ v, no xd needed)
__global__ void fold_att_kernel(const float* __restrict__ W1s, const float* __restrict__ W1d,
                                const float* __restrict__ at1s, const float* __restrict__ at1d,
                                const float* __restrict__ W2s, const float* __restrict__ W2d,
                                const float* __restrict__ at2s, const float* __restrict__ at2d,
                                float* v1s, float* v1d, float* v2s, float* v2d) {
  int tid = blockIdx.x * blockDim.x + threadIdx.x;
  int stride = gridDim.x * blockDim.x;
  for (int o = tid; o < HDIM * HEADS; o += stride) {
    int k = o >> 2, h = o & 3;
    float ss = 0.f, sd = 0.f;
    for (int c = 0; c < CH1; ++c) {
      ss += W1s[k * HC1 + h * CH1 + c] * at1s[h * CH1 + c];
      sd += W1d[k * HC1 + h * CH1 + c] * at1d[h * CH1 + c];
    }
    v1s[o] = ss; v1d[o] = sd;
  }
  for (int o = tid; o < HC1 * HEADS; o += stride) {
    int k = o >> 2, h = o & 3;
    float ss = 0.f, sd = 0.f;
    for (int c = 0; c < CH2; ++c) {
      ss += W2s[k * HC2 + h * CH2 + c] * at2s[h * CH2 + c];
      sd += W2d[k * HC2 + h * CH2 + c] * at2d[h * CH2 + c];
    }
    v2s[o] = ss; v2d[o] = sd;
  }
}

// ---------------- fp32 tiled GEMM: C[N,M] = A[:,acol:acol+K] @ B + bias ----------------
// BN=64 rows x BM=64 cols per block, BK=32, 256 threads, 4x4 microtile.
// N must be a multiple of 64 (40000 = 625*64).
#define BN 64
#define BM 64
#define BK 32
__launch_bounds__(256)
__global__ void gemm_kernel(const float* __restrict__ A, int lda, int acol, int K,
                            const float* __restrict__ B, int ldb,
                            float* __restrict__ C, __hip_bfloat16* __restrict__ Cbf,
                            int ldc, int ccol,
                            const float* __restrict__ bias) {
  __shared__ float As[BK][BN + 1];
  __shared__ float Bs[BK][BM];
  int tid = threadIdx.x;
  int tx = tid & 15, ty = tid >> 4;
  int r0 = blockIdx.y * BN;
  int c0 = blockIdx.x * BM;
  float acc[4][4] = {};

  for (int k0 = 0; k0 < K; k0 += BK) {
    // A tile: thread -> row = tid>>2, kq = (tid&3)*8; 8 consecutive k per thread
    {
      int row = tid >> 2, kq = (tid & 3) * 8;
      const float* ap = A + (size_t)(r0 + row) * lda + acol + k0 + kq;
#pragma unroll
      for (int j = 0; j < 8; ++j) {
        int kk = k0 + kq + j;
        As[kq + j][row] = (kk < K) ? ap[j] : 0.f;
      }
    }
    // B tile: idx -> k = idx>>6, m = idx&63 (coalesced over m)
    {
#pragma unroll
      for (int i = 0; i < 8; ++i) {
        int idx = tid + i * 256;
        int k = idx >> 6, m = idx & 63;
        float v = 0.f;
        if (k0 + k < K) v = B[(size_t)(k0 + k) * ldb + c0 + m];
        Bs[k][m] = v;
      }
    }
    __syncthreads();
#pragma unroll
    for (int k = 0; k < BK; ++k) {
      float4 b = *(const float4*)&Bs[k][tx * 4];
      float ar[4];
#pragma unroll
      for (int r = 0; r < 4; ++r) ar[r] = As[k][ty * 4 + r];
#pragma unroll
      for (int r = 0; r < 4; ++r) {
        acc[r][0] += ar[r] * b.x;
        acc[r][1] += ar[r] * b.y;
        acc[r][2] += ar[r] * b.z;
        acc[r][3] += ar[r] * b.w;
      }
    }
    __syncthreads();
  }
#pragma unroll
  for (int r = 0; r < 4; ++r) {
    int row = r0 + ty * 4 + r;
#pragma unroll
    for (int j = 0; j < 4; ++j) {
      int col = c0 + tx * 4 + j;
      float v = acc[r][j];
      if (bias) v += bias[col];
      if (C)   C[(size_t)row * ldc + ccol + col] = v;
      if (Cbf) Cbf[(size_t)row * ldc + ccol + col] = __float2bfloat16(v);
    }
  }
}

// ---------------- attention logits: a_s/a_d[N,4] = h[N,K] @ v[K,4] ----------------
__launch_bounds__(256)
__global__ void attn_proj_kernel(const float* __restrict__ h, int K,
                                 const float* __restrict__ vs, const float* __restrict__ vd,
                                 float* __restrict__ a_s, float* __restrict__ a_d, int N) {
  extern __shared__ float lds[];      // VsT[4][K] then VdT[4][K]
  float* VsT = lds;
  float* VdT = lds + 4 * K;
  for (int idx = threadIdx.x; idx < 4 * K; idx += 256) {
    int j = idx / K, k = idx - j * K;
    VsT[j * K + k] = vs[k * 4 + j];
    VdT[j * K + k] = vd[k * 4 + j];
  }
  __syncthreads();
  int wave = threadIdx.x >> 6, lane = threadIdx.x & 63;
  int n = blockIdx.x * 4 + wave;
  if (n >= N) return;
  float as[4] = {0.f, 0.f, 0.f, 0.f}, ad[4] = {0.f, 0.f, 0.f, 0.f};
  const float* hp = h + (size_t)n * K;
  for (int k = lane; k < K; k += 64) {
    float hv = hp[k];
#pragma unroll
    for (int j = 0; j < 4; ++j) {
      as[j] += hv * VsT[j * K + k];
      ad[j] += hv * VdT[j * K + k];
    }
  }
#pragma unroll
  for (int j = 0; j < 4; ++j) {
    for (int o = 32; o; o >>= 1) {
      as[j] += __shfl_xor(as[j], o);
      ad[j] += __shfl_xor(ad[j], o);
    }
  }
  if (lane == 0) {
#pragma unroll
    for (int j = 0; j < 4; ++j) {
      a_s[(size_t)n * 4 + j] = as[j];
      a_d[(size_t)n * 4 + j] = ad[j];
    }
  }
}

// ---------------- per-dst segment softmax (stores unnormalized p + 1/denom) -------------
__launch_bounds__(256)
__global__ void edge_softmax_kernel(const int* __restrict__ off, const int* __restrict__ srcs,
                                    const float* __restrict__ a_s, const float* __restrict__ a_d,
                                    float* __restrict__ alpha, float* __restrict__ rden, int N) {
  int wave = threadIdx.x >> 6, lane = threadIdx.x & 63;
  int n = blockIdx.x * 4 + wave;
  if (n >= N) return;
  int s0 = off[n], s1 = off[n + 1];
  float4 ad = *(const float4*)&a_d[(size_t)n * 4];
  float mx = -1e30f, my = -1e30f, mz = -1e30f, mw = -1e30f;
  for (int i = s0 + lane; i < s1; i += 64) {
    float4 as = *(const float4*)&a_s[(size_t)srcs[i] * 4];
    mx = fmaxf(mx, lrelu(as.x + ad.x));
    my = fmaxf(my, lrelu(as.y + ad.y));
    mz = fmaxf(mz, lrelu(as.z + ad.z));
    mw = fmaxf(mw, lrelu(as.w + ad.w));
  }
  for (int o = 32; o; o >>= 1) {
    mx = fmaxf(mx, __shfl_xor(mx, o));
    my = fmaxf(my, __shfl_xor(my, o));
    mz = fmaxf(mz, __shfl_xor(mz, o));
    mw = fmaxf(mw, __shfl_xor(mw, o));
  }
  float sx = 0.f, sy = 0.f, sz = 0.f, sw = 0.f;
  for (int i = s0 + lane; i < s1; i += 64) {
    float4 as = *(const float4*)&a_s[(size_t)srcs[i] * 4];
    float4 p;
    p.x = expf(lrelu(as.x + ad.x) - mx);
    p.y = expf(lrelu(as.y + ad.y) - my);
    p.z = expf(lrelu(as.z + ad.z) - mz);
    p.w = expf(lrelu(as.w + ad.w) - mw);
    sx += p.x; sy += p.y; sz += p.z; sw += p.w;
    *(float4*)&alpha[(size_t)i * 4] = p;
  }
  for (int o = 32; o; o >>= 1) {
    sx += __shfl_xor(sx, o);
    sy += __shfl_xor(sy, o);
    sz += __shfl_xor(sz, o);
    sw += __shfl_xor(sw, o);
  }
  if (lane == 0) {
    float4 r;
    r.x = sx > 0.f ? 1.f / sx : 0.f;
    r.y = sy > 0.f ? 1.f / sy : 0.f;
    r.z = sz > 0.f ? 1.f / sz : 0.f;
    r.w = sw > 0.f ? 1.f / sw : 0.f;
    *(float4*)&rden[(size_t)n * 4] = r;
  }
}

// ---------------- weighted aggregate + bias + skip (+relu) ----------------
template <int VEC>
__device__ __forceinline__ void load_bf(const unsigned short* p, float* out);
template <>
__device__ __forceinline__ void load_bf<4>(const unsigned short* p, float* out) {
  uint2 q = *(const uint2*)p;
  out[0] = bf2f(q.x & 0xffffu); out[1] = bf2f(q.x >> 16);
  out[2] = bf2f(q.y & 0xffffu); out[3] = bf2f(q.y >> 16);
}
template <>
__device__ __forceinline__ void load_bf<2>(const unsigned short* p, float* out) {
  unsigned int q = *(const unsigned int*)p;
  out[0] = bf2f(q & 0xffffu); out[1] = bf2f(q >> 16);
}

template <int CH, int VEC, bool RELU>
__launch_bounds__(256)
__global__ void aggregate_kernel(const int* __restrict__ off, const int* __restrict__ srcs,
                                 const float* __restrict__ alpha, const float* __restrict__ rden,
                                 const unsigned short* __restrict__ xs,
                                 const float* __restrict__ bias,
                                 const float* __restrict__ skip,
                                 float* __restrict__ out, int N) {
  const int HC = 4 * CH;
  int wave = threadIdx.x >> 6, lane = threadIdx.x & 63;
  int n = blockIdx.x * 4 + wave;
  if (n >= N) return;
  int h = lane >> 4;
  int c = (lane & 15) * VEC;
  int i = off[n], end = off[n + 1];
  float acc[VEC];
#pragma unroll
  for (int v = 0; v < VEC; ++v) acc[v] = 0.f;
  for (; i + 2 <= end; i += 2) {
    int sA = srcs[i], sB = srcs[i + 1];
    float wA = alpha[(size_t)i * 4 + h];
    float wB = alpha[(size_t)(i + 1) * 4 + h];
    float xA[VEC], xB[VEC];
    load_bf<VEC>(xs + (size_t)sA * HC + h * CH + c, xA);
    load_bf<VEC>(xs + (size_t)sB * HC + h * CH + c, xB);
#pragma unroll
    for (int v = 0; v < VEC; ++v) acc[v] += wA * xA[v] + wB * xB[v];
  }
  if (i < end) {
    int sA = srcs[i];
    float wA = alpha[(size_t)i * 4 + h];
    float xA[VEC];
    load_bf<VEC>(xs + (size_t)sA * HC + h * CH + c, xA);
#pragma unroll
    for (int v = 0; v < VEC; ++v) acc[v] += wA * xA[v];
  }
  float r = rden[(size_t)n * 4 + h];
  size_t obase = (size_t)n * HC + h * CH + c;
#pragma unroll
  for (int v = 0; v < VEC; ++v) {
    float val = acc[v] * r + bias[h * CH + c + v] + skip[obase + v];
    if (RELU) val = fmaxf(val, 0.f);
    out[obase + v] = val;
  }
}

// ---------------- host launch ----------------
extern "C" void kernel_launch(void* const* d_in, const int* in_sizes, int n_in,
                              void* d_out, int out_size, void* d_ws, size_t ws_size,
                              hipStream_t stream) {
  const float* x      = (const float*)d_in[0];
  const int*   ei     = (const int*)d_in[1];
  const float* W_rna  = (const float*)d_in[3];
  const float* b_rna  = (const float*)d_in[4];
  const float* W_prot = (const float*)d_in[5];
  const float* b_prot = (const float*)d_in[6];
  const float* W1s    = (const float*)d_in[7];
  const float* W1d    = (const float*)d_in[8];
  const float* at1s   = (const float*)d_in[9];
  const float* at1d   = (const float*)d_in[10];
  const float* bias1  = (const float*)d_in[11];
  const float* Wl1    = (const float*)d_in[12];
  const float* bl1    = (const float*)d_in[13];
  const float* W2s    = (const float*)d_in[14];
  const float* W2d    = (const float*)d_in[15];
  const float* at2s   = (const float*)d_in[16];
  const float* at2d   = (const float*)d_in[17];
  const float* bias2  = (const float*)d_in[18];
  const float* Wl2    = (const float*)d_in[19];
  const float* bl2    = (const float*)d_in[20];

  const int N = in_sizes[0] / D_IN;   // 40000 (multiple of 64 and 4)
  const int E = in_sizes[1] / 2;      // 640000
  const int* srcv = ei;
  const int* dstv = ei + E;

  char* ws = (char*)d_ws;
  size_t o = 0;
  auto carve = [&](size_t bytes) {
    void* p = ws + o;
    o += (bytes + 255) & ~(size_t)255;
    return p;
  };
  int* deg    = (int*)carve((size_t)N * 4);
  int* offp   = (int*)carve((size_t)(N + 1) * 4);
  int* cur    = (int*)carve((size_t)N * 4);
  int* srcs   = (int*)carve((size_t)E * 4);
  float* v1s  = (float*)carve(HDIM * HEADS * 4);
  float* v1d  = (float*)carve(HDIM * HEADS * 4);
  float* v2s  = (float*)carve(HC1 * HEADS * 4);
  float* v2d  = (float*)carve(HC1 * HEADS * 4);
  float* a_s  = (float*)carve((size_t)N * 4 * 4);
  float* a_d  = (float*)carve((size_t)N * 4 * 4);
  float* rden = (float*)carve((size_t)N * 4 * 4);
  float* alpha = (float*)carve((size_t)E * 4 * 4);
  float* h0   = (float*)carve((size_t)N * HDIM * 4);
  unsigned short* xs1 = (unsigned short*)carve((size_t)N * HC1 * 2);
  float* z1   = (float*)carve((size_t)N * HC1 * 4);
  float* h1   = (float*)carve((size_t)N * HC1 * 4);
  // layer-2 reuse (lifetimes disjoint):
  unsigned short* xs2 = (unsigned short*)h0;  // h0 dead after layer-1 GEMMs/proj
  float* z2 = z1;                             // z1 dead after aggregate-1
  float* out = (float*)d_out;

  // 1. counting-sort edges by dst
  zero_i32<<<(N + 255) / 256, 256, 0, stream>>>(deg, N);
  hist_kernel<<<(E + 255) / 256, 256, 0, stream>>>(dstv, deg, E);
  scan_kernel<<<1, 1024, 0, stream>>>(deg, offp, cur, N);
  scatter_kernel<<<(E + 255) / 256, 256, 0, stream>>>(srcv, dstv, cur, srcs, E);
  // 2. fold attention vectors
  fold_att_kernel<<<8, 256, 0, stream>>>(W1s, W1d, at1s, at1d, W2s, W2d, at2s, at2d,
                                         v1s, v1d, v2s, v2d);
  // 3. embedding -> h0[N,128]
  gemm_kernel<<<dim3(1, N / 64), 256, 0, stream>>>(x, D_IN, 0, D_RNA, W_rna, 64,
                                                   h0, nullptr, HDIM, 0, b_rna);
  gemm_kernel<<<dim3(1, N / 64), 256, 0, stream>>>(x, D_IN, D_RNA, D_PROT, W_prot, 64,
                                                   h0, nullptr, HDIM, 64, b_prot);
  // 4. layer-1 projections
  gemm_kernel<<<dim3(HC1 / 64, N / 64), 256, 0, stream>>>(h0, HDIM, 0, HDIM, W1s, HC1,
                                                          nullptr, (__hip_bfloat16*)xs1, HC1, 0, nullptr);
  gemm_kernel<<<dim3(HC1 / 64, N / 64), 256, 0, stream>>>(h0, HDIM, 0, HDIM, Wl1, HC1,
                                                          z1, nullptr, HC1, 0, bl1);
  attn_proj_kernel<<<N / 4, 256, 8 * HDIM * 4, stream>>>(h0, HDIM, v1s, v1d, a_s, a_d, N);
  // 5. layer-1 edge softmax + aggregate -> h1 = relu(agg + bias1 + z1)
  edge_softmax_kernel<<<N / 4, 256, 0, stream>>>(offp, srcs, a_s, a_d, alpha, rden, N);
  aggregate_kernel<CH1, 4, true><<<N / 4, 256, 0, stream>>>(offp, srcs, alpha, rden, xs1,
                                                            bias1, z1, h1, N);
  // 6. layer-2
  gemm_kernel<<<dim3(HC2 / 64, N / 64), 256, 0, stream>>>(h1, HC1, 0, HC1, W2s, HC2,
                                                          nullptr, (__hip_bfloat16*)xs2, HC2, 0, nullptr);
  attn_proj_kernel<<<N / 4, 256, 8 * HC1 * 4, stream>>>(h1, HC1, v2s, v2d, a_s, a_d, N);
  gemm_kernel<<<dim3(HC2 / 64, N / 64), 256, 0, stream>>>(h1, HC1, 0, HC1, Wl2, HC2,
                                                          z2, nullptr, HC2, 0, bl2);
  edge_softmax_kernel<<<N / 4, 256, 0, stream>>>(offp, srcs, a_s, a_d, alpha, rden, N);
  aggregate_kernel<CH2, 2, false><<<N / 4, 256, 0, stream>>>(offp, srcs, alpha, rden, xs2,
                                                             bias2, z2, out, N);
}

// Round 2
// 1153.207 us; speedup vs baseline: 1.1147x; 1.1147x over previous
//
#include <hip/hip_runtime.h>
#include <hip/hip_bf16.h>
#include <stdint.h>

// GraRPINet: 2-layer GAT. N=40000 nodes, E=640000 edges.
// R2: split-K atomic embedding GEMM (fix 625-block latency bind: VALUBusy 20%,
// occ 28% -> target 15 blocks/CU), float4 A-staging, fast scan, 16-lane softmax.

#define HEADS 4
#define CH1   64
#define CH2   32
#define HC1   256   // HEADS*CH1
#define HC2   128   // HEADS*CH2

static constexpr int D_RNA  = 1000;
static constexpr int D_PROT = 300;
static constexpr int D_IN   = 1300;
static constexpr int HDIM   = 128;  // 2H

__device__ __forceinline__ float lrelu(float x) { return x >= 0.f ? x : 0.2f * x; }
__device__ __forceinline__ float bf2f(unsigned int u16) {
  return __uint_as_float(u16 << 16);
}

// ---------------- small utility kernels ----------------
__global__ void zero_i32(int* p, int n) {
  int i = blockIdx.x * 256 + threadIdx.x;
  if (i < n) p[i] = 0;
}

__global__ void init_h0_bias(float* __restrict__ h0, const float* __restrict__ b_rna,
                             const float* __restrict__ b_prot, int total) {
  int i = blockIdx.x * 256 + threadIdx.x;
  if (i < total) {
    int c = i & (HDIM - 1);
    h0[i] = (c < 64) ? b_rna[c] : b_prot[c - 64];
  }
}

__global__ void hist_kernel(const int* __restrict__ dstv, int* __restrict__ deg, int E) {
  int i = blockIdx.x * 256 + threadIdx.x;
  if (i < E) atomicAdd(&deg[dstv[i]], 1);
}

// single block: thread-local serial sums + one 1024-wide scan (2 global passes, ~20 barriers)
__global__ void scan_kernel(const int* __restrict__ deg, int* __restrict__ off,
                            int* __restrict__ cur, int n) {
  __shared__ int s[1024];
  int tid = threadIdx.x;
  const int CHK = (n + 1023) / 1024;
  int base = tid * CHK;
  int sum = 0;
  for (int j = 0; j < CHK; ++j) {
    int i = base + j;
    if (i < n) sum += deg[i];
  }
  s[tid] = sum;
  __syncthreads();
  for (int o = 1; o < 1024; o <<= 1) {
    int t = (tid >= o) ? s[tid - o] : 0;
    __syncthreads();
    s[tid] += t;
    __syncthreads();
  }
  int run = s[tid] - sum;  // exclusive prefix of this thread's chunk
  for (int j = 0; j < CHK; ++j) {
    int i = base + j;
    if (i < n) {
      off[i] = run; cur[i] = run;
      run += deg[i];
    }
  }
  if (tid == 1023) off[n] = s[1023];
}

__global__ void scatter_kernel(const int* __restrict__ srcv, const int* __restrict__ dstv,
                               int* __restrict__ cur, int* __restrict__ srcs, int E) {
  int i = blockIdx.x * 256 + threadIdx.x;
  if (i < E) {
    int d = dstv[i];
    int pos = atomicAdd(&cur[d], 1);
    srcs[pos] = srcv[i];
  }
}

// fold att vectors: v[k,h] = sum_c W[k, h*CH+c] * att[h,c]  (so a = h @ v, no xd needed)
__global__ void fold_att_kernel(const float* __restrict__ W1s, const float* __restrict__ W1d,
                                const float* __restrict__ at1s, const float* __restrict__ at1d,
                                const float* __restrict__ W2s, const float* __restrict__ W2d,
                                const float* __restrict__ at2s, const float* __restrict__ at2d,
                                float* v1s, float* v1d, float* v2s, float* v2d) {
  int tid = blockIdx.x * blockDim.x + threadIdx.x;
  int stride = gridDim.x * blockDim.x;
  for (int o = tid; o < HDIM * HEADS; o += stride) {
    int k = o >> 2, h = o & 3;
    float ss = 0.f, sd = 0.f;
    for (int c = 0; c < CH1; ++c) {
      ss += W1s[k * HC1 + h * CH1 + c] * at1s[h * CH1 + c];
      sd += W1d[k * HC1 + h * CH1 + c] * at1d[h * CH1 + c];
    }
    v1s[o] = ss; v1d[o] = sd;
  }
  for (int o = tid; o < HC1 * HEADS; o += stride) {
    int k = o >> 2, h = o & 3;
    float ss = 0.f, sd = 0.f;
    for (int c = 0; c < CH2; ++c) {
      ss += W2s[k * HC2 + h * CH2 + c] * at2s[h * CH2 + c];
      sd += W2d[k * HC2 + h * CH2 + c] * at2d[h * CH2 + c];
    }
    v2s[o] = ss; v2d[o] = sd;
  }
}

// ---------------- fp32 tiled GEMM: C[N,M] (+)= A[:,acol+kbeg:acol+kend] @ B ----------------
// BN=64 rows x BM=64 cols per block, BK=32, 256 threads, 4x4 microtile.
// ATOMIC: atomicAdd epilogue (C pre-initialized with bias), used for split-K embedding.
#define BN 64
#define BM 64
#define BK 32
template <bool ATOMIC>
__launch_bounds__(256)
__global__ void gemm_kernel(const float* __restrict__ A, int lda, int acol, int K,
                            int kchunk,
                            const float* __restrict__ B, int ldb,
                            float* __restrict__ C, __hip_bfloat16* __restrict__ Cbf,
                            int ldc, int ccol,
                            const float* __restrict__ bias) {
  __shared__ float As[BK][BN + 1];
  __shared__ float Bs[BK][BM];
  int tid = threadIdx.x;
  int tx = tid & 15, ty = tid >> 4;
  int r0 = blockIdx.y * BN;
  int c0 = blockIdx.x * BM;
  int k_begin = blockIdx.z * kchunk;
  int k_end   = min(K, k_begin + kchunk);
  float acc[4][4] = {};

  for (int k0 = k_begin; k0 < k_end; k0 += BK) {
    // A tile: row = tid>>2, kq = (tid&3)*8; 16B-aligned float4 pairs when fully in-range
    {
      int row = tid >> 2, kq = (tid & 3) * 8;
      const float* ap = A + (size_t)(r0 + row) * lda + acol + k0 + kq;
      if (k0 + kq + 8 <= k_end) {
        float4 u = *(const float4*)ap;
        float4 v = *(const float4*)(ap + 4);
        As[kq + 0][row] = u.x; As[kq + 1][row] = u.y;
        As[kq + 2][row] = u.z; As[kq + 3][row] = u.w;
        As[kq + 4][row] = v.x; As[kq + 5][row] = v.y;
        As[kq + 6][row] = v.z; As[kq + 7][row] = v.w;
      } else {
#pragma unroll
        for (int j = 0; j < 8; ++j) {
          int kk = k0 + kq + j;
          As[kq + j][row] = (kk < k_end) ? ap[j] : 0.f;
        }
      }
    }
    // B tile: idx -> k = idx>>6, m = idx&63 (coalesced over m)
    {
#pragma unroll
      for (int i = 0; i < 8; ++i) {
        int idx = tid + i * 256;
        int k = idx >> 6, m = idx & 63;
        float v = 0.f;
        if (k0 + k < k_end) v = B[(size_t)(k0 + k) * ldb + c0 + m];
        Bs[k][m] = v;
      }
    }
    __syncthreads();
#pragma unroll
    for (int k = 0; k < BK; ++k) {
      float4 b = *(const float4*)&Bs[k][tx * 4];
      float ar[4];
#pragma unroll
      for (int r = 0; r < 4; ++r) ar[r] = As[k][ty * 4 + r];
#pragma unroll
      for (int r = 0; r < 4; ++r) {
        acc[r][0] += ar[r] * b.x;
        acc[r][1] += ar[r] * b.y;
        acc[r][2] += ar[r] * b.z;
        acc[r][3] += ar[r] * b.w;
      }
    }
    __syncthreads();
  }
#pragma unroll
  for (int r = 0; r < 4; ++r) {
    int row = r0 + ty * 4 + r;
#pragma unroll
    for (int j = 0; j < 4; ++j) {
      int col = c0 + tx * 4 + j;
      float v = acc[r][j];
      if (ATOMIC) {
        atomicAdd(&C[(size_t)row * ldc + ccol + col], v);
      } else {
        if (bias) v += bias[col];
        if (C)   C[(size_t)row * ldc + ccol + col] = v;
        if (Cbf) Cbf[(size_t)row * ldc + ccol + col] = __float2bfloat16(v);
      }
    }
  }
}

// ---------------- attention logits: a_s/a_d[N,4] = h[N,K] @ v[K,4] ----------------
__launch_bounds__(256)
__global__ void attn_proj_kernel(const float* __restrict__ h, int K,
                                 const float* __restrict__ vs, const float* __restrict__ vd,
                                 float* __restrict__ a_s, float* __restrict__ a_d, int N) {
  extern __shared__ float lds[];      // VsT[4][K] then VdT[4][K]
  float* VsT = lds;
  float* VdT = lds + 4 * K;
  for (int idx = threadIdx.x; idx < 4 * K; idx += 256) {
    int j = idx / K, k = idx - j * K;
    VsT[j * K + k] = vs[k * 4 + j];
    VdT[j * K + k] = vd[k * 4 + j];
  }
  __syncthreads();
  int wave = threadIdx.x >> 6, lane = threadIdx.x & 63;
  int n = blockIdx.x * 4 + wave;
  if (n >= N) return;
  float as[4] = {0.f, 0.f, 0.f, 0.f}, ad[4] = {0.f, 0.f, 0.f, 0.f};
  const float* hp = h + (size_t)n * K;
  for (int k = lane; k < K; k += 64) {
    float hv = hp[k];
#pragma unroll
    for (int j = 0; j < 4; ++j) {
      as[j] += hv * VsT[j * K + k];
      ad[j] += hv * VdT[j * K + k];
    }
  }
#pragma unroll
  for (int j = 0; j < 4; ++j) {
    for (int o = 32; o; o >>= 1) {
      as[j] += __shfl_xor(as[j], o);
      ad[j] += __shfl_xor(ad[j], o);
    }
  }
  if (lane == 0) {
#pragma unroll
    for (int j = 0; j < 4; ++j) {
      a_s[(size_t)n * 4 + j] = as[j];
      a_d[(size_t)n * 4 + j] = ad[j];
    }
  }
}

// -------- per-dst segment softmax: 16 lanes per node (avg degree 16), 4 nodes/wave --------
__launch_bounds__(256)
__global__ void edge_softmax_kernel(const int* __restrict__ off, const int* __restrict__ srcs,
                                    const float* __restrict__ a_s, const float* __restrict__ a_d,
                                    float* __restrict__ alpha, float* __restrict__ rden, int N) {
  int lane = threadIdx.x & 63;
  int wave = threadIdx.x >> 6;
  int g = lane >> 4, l = lane & 15;
  int n = (blockIdx.x * 4 + wave) * 4 + g;   // N multiple of 16
  if (n >= N) return;
  int s0 = off[n], s1 = off[n + 1];
  float4 ad = *(const float4*)&a_d[(size_t)n * 4];
  float mx = -1e30f, my = -1e30f, mz = -1e30f, mw = -1e30f;
  for (int i = s0 + l; i < s1; i += 16) {
    float4 as = *(const float4*)&a_s[(size_t)srcs[i] * 4];
    mx = fmaxf(mx, lrelu(as.x + ad.x));
    my = fmaxf(my, lrelu(as.y + ad.y));
    mz = fmaxf(mz, lrelu(as.z + ad.z));
    mw = fmaxf(mw, lrelu(as.w + ad.w));
  }
#pragma unroll
  for (int o = 1; o < 16; o <<= 1) {
    mx = fmaxf(mx, __shfl_xor(mx, o));
    my = fmaxf(my, __shfl_xor(my, o));
    mz = fmaxf(mz, __shfl_xor(mz, o));
    mw = fmaxf(mw, __shfl_xor(mw, o));
  }
  float sx = 0.f, sy = 0.f, sz = 0.f, sw = 0.f;
  for (int i = s0 + l; i < s1; i += 16) {
    float4 as = *(const float4*)&a_s[(size_t)srcs[i] * 4];
    float4 p;
    p.x = expf(lrelu(as.x + ad.x) - mx);
    p.y = expf(lrelu(as.y + ad.y) - my);
    p.z = expf(lrelu(as.z + ad.z) - mz);
    p.w = expf(lrelu(as.w + ad.w) - mw);
    sx += p.x; sy += p.y; sz += p.z; sw += p.w;
    *(float4*)&alpha[(size_t)i * 4] = p;
  }
#pragma unroll
  for (int o = 1; o < 16; o <<= 1) {
    sx += __shfl_xor(sx, o);
    sy += __shfl_xor(sy, o);
    sz += __shfl_xor(sz, o);
    sw += __shfl_xor(sw, o);
  }
  if (l == 0) {
    float4 r;
    r.x = sx > 0.f ? 1.f / sx : 0.f;
    r.y = sy > 0.f ? 1.f / sy : 0.f;
    r.z = sz > 0.f ? 1.f / sz : 0.f;
    r.w = sw > 0.f ? 1.f / sw : 0.f;
    *(float4*)&rden[(size_t)n * 4] = r;
  }
}

// ---------------- weighted aggregate + bias + skip (+relu) ----------------
template <int VEC>
__device__ __forceinline__ void load_bf(const unsigned short* p, float* out);
template <>
__device__ __forceinline__ void load_bf<4>(const unsigned short* p, float* out) {
  uint2 q = *(const uint2*)p;
  out[0] = bf2f(q.x & 0xffffu); out[1] = bf2f(q.x >> 16);
  out[2] = bf2f(q.y & 0xffffu); out[3] = bf2f(q.y >> 16);
}
template <>
__device__ __forceinline__ void load_bf<2>(const unsigned short* p, float* out) {
  unsigned int q = *(const unsigned int*)p;
  out[0] = bf2f(q & 0xffffu); out[1] = bf2f(q >> 16);
}

template <int CH, int VEC, bool RELU>
__launch_bounds__(256)
__global__ void aggregate_kernel(const int* __restrict__ off, const int* __restrict__ srcs,
                                 const float* __restrict__ alpha, const float* __restrict__ rden,
                                 const unsigned short* __restrict__ xs,
                                 const float* __restrict__ bias,
                                 const float* __restrict__ skip,
                                 float* __restrict__ out, int N) {
  const int HC = 4 * CH;
  int wave = threadIdx.x >> 6, lane = threadIdx.x & 63;
  int n = blockIdx.x * 4 + wave;
  if (n >= N) return;
  int h = lane >> 4;
  int c = (lane & 15) * VEC;
  int i = off[n], end = off[n + 1];
  float acc[VEC];
#pragma unroll
  for (int v = 0; v < VEC; ++v) acc[v] = 0.f;
  for (; i + 2 <= end; i += 2) {
    int sA = srcs[i], sB = srcs[i + 1];
    float wA = alpha[(size_t)i * 4 + h];
    float wB = alpha[(size_t)(i + 1) * 4 + h];
    float xA[VEC], xB[VEC];
    load_bf<VEC>(xs + (size_t)sA * HC + h * CH + c, xA);
    load_bf<VEC>(xs + (size_t)sB * HC + h * CH + c, xB);
#pragma unroll
    for (int v = 0; v < VEC; ++v) acc[v] += wA * xA[v] + wB * xB[v];
  }
  if (i < end) {
    int sA = srcs[i];
    float wA = alpha[(size_t)i * 4 + h];
    float xA[VEC];
    load_bf<VEC>(xs + (size_t)sA * HC + h * CH + c, xA);
#pragma unroll
    for (int v = 0; v < VEC; ++v) acc[v] += wA * xA[v];
  }
  float r = rden[(size_t)n * 4 + h];
  size_t obase = (size_t)n * HC + h * CH + c;
#pragma unroll
  for (int v = 0; v < VEC; ++v) {
    float val = acc[v] * r + bias[h * CH + c + v] + skip[obase + v];
    if (RELU) val = fmaxf(val, 0.f);
    out[obase + v] = val;
  }
}

// ---------------- host launch ----------------
extern "C" void kernel_launch(void* const* d_in, const int* in_sizes, int n_in,
                              void* d_out, int out_size, void* d_ws, size_t ws_size,
                              hipStream_t stream) {
  const float* x      = (const float*)d_in[0];
  const int*   ei     = (const int*)d_in[1];
  const float* W_rna  = (const float*)d_in[3];
  const float* b_rna  = (const float*)d_in[4];
  const float* W_prot = (const float*)d_in[5];
  const float* b_prot = (const float*)d_in[6];
  const float* W1s    = (const float*)d_in[7];
  const float* W1d    = (const float*)d_in[8];
  const float* at1s   = (const float*)d_in[9];
  const float* at1d   = (const float*)d_in[10];
  const float* bias1  = (const float*)d_in[11];
  const float* Wl1    = (const float*)d_in[12];
  const float* bl1    = (const float*)d_in[13];
  const float* W2s    = (const float*)d_in[14];
  const float* W2d    = (const float*)d_in[15];
  const float* at2s   = (const float*)d_in[16];
  const float* at2d   = (const float*)d_in[17];
  const float* bias2  = (const float*)d_in[18];
  const float* bl2    = (const float*)d_in[20];
  const float* Wl2    = (const float*)d_in[19];

  const int N = in_sizes[0] / D_IN;   // 40000
  const int E = in_sizes[1] / 2;      // 640000
  const int* srcv = ei;
  const int* dstv = ei + E;

  char* ws = (char*)d_ws;
  size_t o = 0;
  auto carve = [&](size_t bytes) {
    void* p = ws + o;
    o += (bytes + 255) & ~(size_t)255;
    return p;
  };
  int* deg    = (int*)carve((size_t)N * 4);
  int* offp   = (int*)carve((size_t)(N + 1) * 4);
  int* cur    = (int*)carve((size_t)N * 4);
  int* srcs   = (int*)carve((size_t)E * 4);
  float* v1s  = (float*)carve(HDIM * HEADS * 4);
  float* v1d  = (float*)carve(HDIM * HEADS * 4);
  float* v2s  = (float*)carve(HC1 * HEADS * 4);
  float* v2d  = (float*)carve(HC1 * HEADS * 4);
  float* a_s  = (float*)carve((size_t)N * 4 * 4);
  float* a_d  = (float*)carve((size_t)N * 4 * 4);
  float* rden = (float*)carve((size_t)N * 4 * 4);
  float* alpha = (float*)carve((size_t)E * 4 * 4);
  float* h0   = (float*)carve((size_t)N * HDIM * 4);
  unsigned short* xs1 = (unsigned short*)carve((size_t)N * HC1 * 2);
  float* z1   = (float*)carve((size_t)N * HC1 * 4);
  float* h1   = (float*)carve((size_t)N * HC1 * 4);
  unsigned short* xs2 = (unsigned short*)h0;  // h0 dead after layer-1 GEMMs/proj
  float* z2 = z1;                             // z1 dead after aggregate-1
  float* out = (float*)d_out;

  // 1. counting-sort edges by dst
  zero_i32<<<(N + 255) / 256, 256, 0, stream>>>(deg, N);
  hist_kernel<<<(E + 255) / 256, 256, 0, stream>>>(dstv, deg, E);
  scan_kernel<<<1, 1024, 0, stream>>>(deg, offp, cur, N);
  scatter_kernel<<<(E + 255) / 256, 256, 0, stream>>>(srcv, dstv, cur, srcs, E);
  // 2. fold attention vectors
  fold_att_kernel<<<8, 256, 0, stream>>>(W1s, W1d, at1s, at1d, W2s, W2d, at2s, at2d,
                                         v1s, v1d, v2s, v2d);
  // 3. embedding -> h0[N,128]: bias init + split-K atomic GEMMs (4+2 chunks, 3750 blocks)
  init_h0_bias<<<(N * HDIM + 255) / 256, 256, 0, stream>>>(h0, b_rna, b_prot, N * HDIM);
  gemm_kernel<true><<<dim3(1, N / 64, 4), 256, 0, stream>>>(x, D_IN, 0, D_RNA, 256,
                                                            W_rna, 64, h0, nullptr, HDIM, 0, nullptr);
  gemm_kernel<true><<<dim3(1, N / 64, 2), 256, 0, stream>>>(x, D_IN, D_RNA, D_PROT, 160,
                                                            W_prot, 64, h0, nullptr, HDIM, 64, nullptr);
  // 4. layer-1 projections
  gemm_kernel<false><<<dim3(HC1 / 64, N / 64), 256, 0, stream>>>(h0, HDIM, 0, HDIM, HDIM, W1s, HC1,
                                                                 nullptr, (__hip_bfloat16*)xs1, HC1, 0, nullptr);
  gemm_kernel<false><<<dim3(HC1 / 64, N / 64), 256, 0, stream>>>(h0, HDIM, 0, HDIM, HDIM, Wl1, HC1,
                                                                 z1, nullptr, HC1, 0, bl1);
  attn_proj_kernel<<<N / 4, 256, 8 * HDIM * 4, stream>>>(h0, HDIM, v1s, v1d, a_s, a_d, N);
  // 5. layer-1 edge softmax + aggregate -> h1 = relu(agg + bias1 + z1)
  edge_softmax_kernel<<<N / 16, 256, 0, stream>>>(offp, srcs, a_s, a_d, alpha, rden, N);
  aggregate_kernel<CH1, 4, true><<<N / 4, 256, 0, stream>>>(offp, srcs, alpha, rden, xs1,
                                                            bias1, z1, h1, N);
  // 6. layer-2
  gemm_kernel<false><<<dim3(HC2 / 64, N / 64), 256, 0, stream>>>(h1, HC1, 0, HC1, HC1, W2s, HC2,
                                                                 nullptr, (__hip_bfloat16*)xs2, HC2, 0, nullptr);
  attn_proj_kernel<<<N / 4, 256, 8 * HC1 * 4, stream>>>(h1, HC1, v2s, v2d, a_s, a_d, N);
  gemm_kernel<false><<<dim3(HC2 / 64, N / 64), 256, 0, stream>>>(h1, HC1, 0, HC1, HC1, Wl2, HC2,
                                                                 z2, nullptr, HC2, 0, bl2);
  edge_softmax_kernel<<<N / 16, 256, 0, stream>>>(offp, srcs, a_s, a_d, alpha, rden, N);
  aggregate_kernel<CH2, 2, false><<<N / 4, 256, 0, stream>>>(offp, srcs, alpha, rden, xs2,
                                                             bias2, z2, out, N);
}

// Round 3
// 775.216 us; speedup vs baseline: 1.6583x; 1.4876x over previous
//
#include <hip/hip_runtime.h>
#include <hip/hip_bf16.h>
#include <stdint.h>

// GraRPINet: 2-layer GAT. N=40000 nodes, E=640000 edges.
// R3: all GEMMs -> bf16 MFMA (16x16x32), weights pre-transposed to bf16 BT[n][k],
// h0/h1/z1/z2 stored bf16. No atomics (R2 lesson: atomic split-K = 164MB writes @680GB/s).

#define HEADS 4
#define CH1   64
#define CH2   32
#define HC1   256
#define HC2   128

static constexpr int D_RNA  = 1000;
static constexpr int D_PROT = 300;
static constexpr int D_IN   = 1300;
static constexpr int HDIM   = 128;  // 2H

typedef __bf16 bf16x8 __attribute__((ext_vector_type(8)));
typedef float  f32x4  __attribute__((ext_vector_type(4)));
typedef unsigned short ushort;

__device__ __forceinline__ float lrelu(float x) { return x >= 0.f ? x : 0.2f * x; }
__device__ __forceinline__ float bf2f(unsigned int u16) {
  return __uint_as_float(u16 << 16);
}
__device__ __forceinline__ ushort f2bf(float f) {
  union { float f; unsigned int u; } x; x.f = f;
  unsigned int r = x.u + 0x7fffu + ((x.u >> 16) & 1u);
  return (ushort)(r >> 16);
}

// ---------------- small utility kernels ----------------
__global__ void zero_i32(int* p, int n) {
  int i = blockIdx.x * 256 + threadIdx.x;
  if (i < n) p[i] = 0;
}

__global__ void hist_kernel(const int* __restrict__ dstv, int* __restrict__ deg, int E) {
  int i = blockIdx.x * 256 + threadIdx.x;
  if (i < E) atomicAdd(&deg[dstv[i]], 1);
}

__global__ void scan_kernel(const int* __restrict__ deg, int* __restrict__ off,
                            int* __restrict__ cur, int n) {
  __shared__ int s[1024];
  int tid = threadIdx.x;
  const int CHK = (n + 1023) / 1024;
  int base = tid * CHK;
  int sum = 0;
  for (int j = 0; j < CHK; ++j) {
    int i = base + j;
    if (i < n) sum += deg[i];
  }
  s[tid] = sum;
  __syncthreads();
  for (int o = 1; o < 1024; o <<= 1) {
    int t = (tid >= o) ? s[tid - o] : 0;
    __syncthreads();
    s[tid] += t;
    __syncthreads();
  }
  int run = s[tid] - sum;
  for (int j = 0; j < CHK; ++j) {
    int i = base + j;
    if (i < n) {
      off[i] = run; cur[i] = run;
      run += deg[i];
    }
  }
  if (tid == 1023) off[n] = s[1023];
}

__global__ void scatter_kernel(const int* __restrict__ srcv, const int* __restrict__ dstv,
                               int* __restrict__ cur, int* __restrict__ srcs, int E) {
  int i = blockIdx.x * 256 + threadIdx.x;
  if (i < E) {
    int d = dstv[i];
    int pos = atomicAdd(&cur[d], 1);
    srcs[pos] = srcv[i];
  }
}

// fold att vectors: v[k,h] = sum_c W[k, h*CH+c] * att[h,c]
__global__ void fold_att_kernel(const float* __restrict__ W1s, const float* __restrict__ W1d,
                                const float* __restrict__ at1s, const float* __restrict__ at1d,
                                const float* __restrict__ W2s, const float* __restrict__ W2d,
                                const float* __restrict__ at2s, const float* __restrict__ at2d,
                                float* v1s, float* v1d, float* v2s, float* v2d) {
  int tid = blockIdx.x * blockDim.x + threadIdx.x;
  int stride = gridDim.x * blockDim.x;
  for (int o = tid; o < HDIM * HEADS; o += stride) {
    int k = o >> 2, h = o & 3;
    float ss = 0.f, sd = 0.f;
    for (int c = 0; c < CH1; ++c) {
      ss += W1s[k * HC1 + h * CH1 + c] * at1s[h * CH1 + c];
      sd += W1d[k * HC1 + h * CH1 + c] * at1d[h * CH1 + c];
    }
    v1s[o] = ss; v1d[o] = sd;
  }
  for (int o = tid; o < HC1 * HEADS; o += stride) {
    int k = o >> 2, h = o & 3;
    float ss = 0.f, sd = 0.f;
    for (int c = 0; c < CH2; ++c) {
      ss += W2s[k * HC2 + h * CH2 + c] * at2s[h * CH2 + c];
      sd += W2d[k * HC2 + h * CH2 + c] * at2d[h * CH2 + c];
    }
    v2s[o] = ss; v2d[o] = sd;
  }
}

// ---------------- weight preprocessing: transpose + bf16 ----------------
// BTr[64][1024] (k>=1000 zero), BTp[64][320] (k>=300 zero),
// BT1[512][128] = [W1s|Wl1]^T, BT2[256][256] = [W2s|Wl2]^T, concat biases.
__global__ void convert_weights(const float* __restrict__ W_rna, const float* __restrict__ W_prot,
                                const float* __restrict__ W1s, const float* __restrict__ Wl1,
                                const float* __restrict__ W2s, const float* __restrict__ Wl2,
                                const float* __restrict__ b1, const float* __restrict__ bl1,
                                const float* __restrict__ b2, const float* __restrict__ bl2,
                                ushort* BTr, ushort* BTp, ushort* BT1, ushort* BT2,
                                float* biasL1, float* biasL2) {
  int tid = blockIdx.x * blockDim.x + threadIdx.x;
  int stride = gridDim.x * blockDim.x;
  for (int i = tid; i < 64 * 1024; i += stride) {
    int n = i >> 10, k = i & 1023;
    BTr[i] = (k < D_RNA) ? f2bf(W_rna[k * 64 + n]) : 0;
  }
  for (int i = tid; i < 64 * 320; i += stride) {
    int n = i / 320, k = i - n * 320;
    BTp[i] = (k < D_PROT) ? f2bf(W_prot[k * 64 + n]) : 0;
  }
  for (int i = tid; i < 512 * 128; i += stride) {
    int n = i >> 7, k = i & 127;
    BT1[i] = f2bf(n < 256 ? W1s[k * 256 + n] : Wl1[k * 256 + n - 256]);
  }
  for (int i = tid; i < 256 * 256; i += stride) {
    int n = i >> 8, k = i & 255;
    BT2[i] = f2bf(n < 128 ? W2s[k * 128 + n] : Wl2[k * 128 + n - 128]);
  }
  for (int i = tid; i < 512; i += stride) biasL1[i] = (i < 256) ? b1[i] : bl1[i - 256];
  for (int i = tid; i < 256; i += stride) biasL2[i] = (i < 128) ? b2[i] : bl2[i - 128];
}

#define LDK 72  // padded k-stride (shorts) for 64-wide k tiles: 144B rows -> 2-way-only conflicts

__device__ __forceinline__ f32x4 mfma_bf16(bf16x8 a, bf16x8 b, f32x4 c) {
  return __builtin_amdgcn_mfma_f32_16x16x32_bf16(a, b, c, 0, 0, 0);
}

// ---------------- embedding MFMA GEMM: h0[N,128] bf16 ----------------
// grid (2, N/64): x=0 rna (K=1024 padded), x=1 prot (K=320 padded).
__launch_bounds__(256)
__global__ void embed_gemm(const float* __restrict__ x,
                           const ushort* __restrict__ BTr, const ushort* __restrict__ BTp,
                           const float* __restrict__ b_rna, const float* __restrict__ b_prot,
                           ushort* __restrict__ h0) {
  const bool prot = (blockIdx.x == 1);
  const int Kpad = prot ? 320 : 1024;
  const int acol = prot ? D_RNA : 0;
  const ushort* BT = prot ? BTp : BTr;
  const float* bias = prot ? b_prot : b_rna;
  const int r0 = blockIdx.y * 64;

  __shared__ ushort As[64 * LDK];
  __shared__ ushort Bs[64 * LDK];
  int tid = threadIdx.x;
  int wave = tid >> 6, lane = tid & 63;
  int quad = lane >> 4, lr = lane & 15;
  f32x4 acc[4];
#pragma unroll
  for (int c = 0; c < 4; ++c) acc[c] = (f32x4){0.f, 0.f, 0.f, 0.f};

  int srow = tid >> 2, skq = (tid & 3) * 16;
  for (int k0 = 0; k0 < Kpad; k0 += 64) {
    // A stage: 16 fp32 -> bf16 per thread
    {
      const float* ap = x + (size_t)(r0 + srow) * D_IN + acol + k0 + skq;
      ushort tmp[16];
#pragma unroll
      for (int q = 0; q < 4; ++q) {
        int kg = acol + k0 + skq + q * 4;
        float4 f = (kg + 4 <= D_IN) ? *(const float4*)(ap + q * 4)
                                    : make_float4(0.f, 0.f, 0.f, 0.f);
        tmp[q * 4 + 0] = f2bf(f.x); tmp[q * 4 + 1] = f2bf(f.y);
        tmp[q * 4 + 2] = f2bf(f.z); tmp[q * 4 + 3] = f2bf(f.w);
      }
      *(uint4*)&As[srow * LDK + skq] = *(const uint4*)&tmp[0];
      *(uint4*)&As[srow * LDK + skq + 8] = *(const uint4*)&tmp[8];
    }
    // B stage: bf16 from BT
    {
      const ushort* bp = BT + (size_t)srow * Kpad + k0 + skq;
      *(uint4*)&Bs[srow * LDK + skq] = *(const uint4*)bp;
      *(uint4*)&Bs[srow * LDK + skq + 8] = *(const uint4*)(bp + 8);
    }
    __syncthreads();
    int arow = wave * 16 + lr;
    bf16x8 a0 = *(const bf16x8*)&As[arow * LDK + quad * 8];
    bf16x8 a1 = *(const bf16x8*)&As[arow * LDK + 32 + quad * 8];
#pragma unroll
    for (int c = 0; c < 4; ++c) {
      bf16x8 b0 = *(const bf16x8*)&Bs[(c * 16 + lr) * LDK + quad * 8];
      bf16x8 b1 = *(const bf16x8*)&Bs[(c * 16 + lr) * LDK + 32 + quad * 8];
      acc[c] = mfma_bf16(a0, b0, acc[c]);
      acc[c] = mfma_bf16(a1, b1, acc[c]);
    }
    __syncthreads();
  }
  int colb = prot ? 64 : 0;
#pragma unroll
  for (int c = 0; c < 4; ++c) {
#pragma unroll
    for (int j = 0; j < 4; ++j) {
      int row = r0 + wave * 16 + quad * 4 + j;
      int col = c * 16 + lr;
      h0[(size_t)row * HDIM + colb + col] = f2bf(acc[c][j] + bias[col]);
    }
  }
}

// ---------------- layer MFMA GEMM: [out0|out1][N, halfw each] bf16 = A[N,K]bf16 @ BT^T --------
// grid (OUTW/64, N/64). K = 128 or 256 (multiple of 64).
__launch_bounds__(256)
__global__ void layer_gemm(const ushort* __restrict__ A, int K,
                           const ushort* __restrict__ BT, const float* __restrict__ bias,
                           ushort* __restrict__ out0, ushort* __restrict__ out1, int halfw) {
  const int cb = blockIdx.x * 64;
  const int r0 = blockIdx.y * 64;
  __shared__ ushort As[64 * LDK];
  __shared__ ushort Bs[64 * LDK];
  int tid = threadIdx.x;
  int wave = tid >> 6, lane = tid & 63;
  int quad = lane >> 4, lr = lane & 15;
  f32x4 acc[4];
#pragma unroll
  for (int c = 0; c < 4; ++c) acc[c] = (f32x4){0.f, 0.f, 0.f, 0.f};

  int srow = tid >> 2, skq = (tid & 3) * 16;
  for (int k0 = 0; k0 < K; k0 += 64) {
    {
      const ushort* ap = A + (size_t)(r0 + srow) * K + k0 + skq;
      *(uint4*)&As[srow * LDK + skq] = *(const uint4*)ap;
      *(uint4*)&As[srow * LDK + skq + 8] = *(const uint4*)(ap + 8);
    }
    {
      const ushort* bp = BT + (size_t)(cb + srow) * K + k0 + skq;
      *(uint4*)&Bs[srow * LDK + skq] = *(const uint4*)bp;
      *(uint4*)&Bs[srow * LDK + skq + 8] = *(const uint4*)(bp + 8);
    }
    __syncthreads();
    int arow = wave * 16 + lr;
    bf16x8 a0 = *(const bf16x8*)&As[arow * LDK + quad * 8];
    bf16x8 a1 = *(const bf16x8*)&As[arow * LDK + 32 + quad * 8];
#pragma unroll
    for (int c = 0; c < 4; ++c) {
      bf16x8 b0 = *(const bf16x8*)&Bs[(c * 16 + lr) * LDK + quad * 8];
      bf16x8 b1 = *(const bf16x8*)&Bs[(c * 16 + lr) * LDK + 32 + quad * 8];
      acc[c] = mfma_bf16(a0, b0, acc[c]);
      acc[c] = mfma_bf16(a1, b1, acc[c]);
    }
    __syncthreads();
  }
#pragma unroll
  for (int c = 0; c < 4; ++c) {
#pragma unroll
    for (int j = 0; j < 4; ++j) {
      int row = r0 + wave * 16 + quad * 4 + j;
      int cg = cb + c * 16 + lr;
      ushort v = f2bf(acc[c][j] + bias[cg]);
      if (cg < halfw) out0[(size_t)row * halfw + cg] = v;
      else            out1[(size_t)row * halfw + cg - halfw] = v;
    }
  }
}

// ---------------- attention logits: a_s/a_d[N,4] = h[N,K](bf16) @ v[K,4] ----------------
__launch_bounds__(256)
__global__ void attn_proj_kernel(const ushort* __restrict__ h, int K,
                                 const float* __restrict__ vs, const float* __restrict__ vd,
                                 float* __restrict__ a_s, float* __restrict__ a_d, int N) {
  extern __shared__ float lds[];
  float* VsT = lds;
  float* VdT = lds + 4 * K;
  for (int idx = threadIdx.x; idx < 4 * K; idx += 256) {
    int j = idx / K, k = idx - j * K;
    VsT[j * K + k] = vs[k * 4 + j];
    VdT[j * K + k] = vd[k * 4 + j];
  }
  __syncthreads();
  int wave = threadIdx.x >> 6, lane = threadIdx.x & 63;
  int n = blockIdx.x * 4 + wave;
  if (n >= N) return;
  float as[4] = {0.f, 0.f, 0.f, 0.f}, ad[4] = {0.f, 0.f, 0.f, 0.f};
  const ushort* hp = h + (size_t)n * K;
  for (int k = lane; k < K; k += 64) {
    float hv = bf2f(hp[k]);
#pragma unroll
    for (int j = 0; j < 4; ++j) {
      as[j] += hv * VsT[j * K + k];
      ad[j] += hv * VdT[j * K + k];
    }
  }
#pragma unroll
  for (int j = 0; j < 4; ++j) {
    for (int o = 32; o; o >>= 1) {
      as[j] += __shfl_xor(as[j], o);
      ad[j] += __shfl_xor(ad[j], o);
    }
  }
  if (lane == 0) {
#pragma unroll
    for (int j = 0; j < 4; ++j) {
      a_s[(size_t)n * 4 + j] = as[j];
      a_d[(size_t)n * 4 + j] = ad[j];
    }
  }
}

// -------- per-dst segment softmax: 16 lanes per node, 4 nodes/wave --------
__launch_bounds__(256)
__global__ void edge_softmax_kernel(const int* __restrict__ off, const int* __restrict__ srcs,
                                    const float* __restrict__ a_s, const float* __restrict__ a_d,
                                    float* __restrict__ alpha, float* __restrict__ rden, int N) {
  int lane = threadIdx.x & 63;
  int wave = threadIdx.x >> 6;
  int g = lane >> 4, l = lane & 15;
  int n = (blockIdx.x * 4 + wave) * 4 + g;
  if (n >= N) return;
  int s0 = off[n], s1 = off[n + 1];
  float4 ad = *(const float4*)&a_d[(size_t)n * 4];
  float mx = -1e30f, my = -1e30f, mz = -1e30f, mw = -1e30f;
  for (int i = s0 + l; i < s1; i += 16) {
    float4 as = *(const float4*)&a_s[(size_t)srcs[i] * 4];
    mx = fmaxf(mx, lrelu(as.x + ad.x));
    my = fmaxf(my, lrelu(as.y + ad.y));
    mz = fmaxf(mz, lrelu(as.z + ad.z));
    mw = fmaxf(mw, lrelu(as.w + ad.w));
  }
#pragma unroll
  for (int o = 1; o < 16; o <<= 1) {
    mx = fmaxf(mx, __shfl_xor(mx, o));
    my = fmaxf(my, __shfl_xor(my, o));
    mz = fmaxf(mz, __shfl_xor(mz, o));
    mw = fmaxf(mw, __shfl_xor(mw, o));
  }
  float sx = 0.f, sy = 0.f, sz = 0.f, sw = 0.f;
  for (int i = s0 + l; i < s1; i += 16) {
    float4 as = *(const float4*)&a_s[(size_t)srcs[i] * 4];
    float4 p;
    p.x = expf(lrelu(as.x + ad.x) - mx);
    p.y = expf(lrelu(as.y + ad.y) - my);
    p.z = expf(lrelu(as.z + ad.z) - mz);
    p.w = expf(lrelu(as.w + ad.w) - mw);
    sx += p.x; sy += p.y; sz += p.z; sw += p.w;
    *(float4*)&alpha[(size_t)i * 4] = p;
  }
#pragma unroll
  for (int o = 1; o < 16; o <<= 1) {
    sx += __shfl_xor(sx, o);
    sy += __shfl_xor(sy, o);
    sz += __shfl_xor(sz, o);
    sw += __shfl_xor(sw, o);
  }
  if (l == 0) {
    float4 r;
    r.x = sx > 0.f ? 1.f / sx : 0.f;
    r.y = sy > 0.f ? 1.f / sy : 0.f;
    r.z = sz > 0.f ? 1.f / sz : 0.f;
    r.w = sw > 0.f ? 1.f / sw : 0.f;
    *(float4*)&rden[(size_t)n * 4] = r;
  }
}

// ---------------- weighted aggregate + bias + skip(bf16) (+relu) ----------------
template <int VEC>
__device__ __forceinline__ void load_bf(const ushort* p, float* out);
template <>
__device__ __forceinline__ void load_bf<4>(const ushort* p, float* out) {
  uint2 q = *(const uint2*)p;
  out[0] = bf2f(q.x & 0xffffu); out[1] = bf2f(q.x >> 16);
  out[2] = bf2f(q.y & 0xffffu); out[3] = bf2f(q.y >> 16);
}
template <>
__device__ __forceinline__ void load_bf<2>(const ushort* p, float* out) {
  unsigned int q = *(const unsigned int*)p;
  out[0] = bf2f(q & 0xffffu); out[1] = bf2f(q >> 16);
}

template <int CH, int VEC, bool RELU, bool OUT_BF16>
__launch_bounds__(256)
__global__ void aggregate_kernel(const int* __restrict__ off, const int* __restrict__ srcs,
                                 const float* __restrict__ alpha, const float* __restrict__ rden,
                                 const ushort* __restrict__ xs,
                                 const float* __restrict__ bias,
                                 const ushort* __restrict__ skip,
                                 void* __restrict__ outv, int N) {
  const int HC = 4 * CH;
  int wave = threadIdx.x >> 6, lane = threadIdx.x & 63;
  int n = blockIdx.x * 4 + wave;
  if (n >= N) return;
  int h = lane >> 4;
  int c = (lane & 15) * VEC;
  int i = off[n], end = off[n + 1];
  float acc[VEC];
#pragma unroll
  for (int v = 0; v < VEC; ++v) acc[v] = 0.f;
  for (; i + 2 <= end; i += 2) {
    int sA = srcs[i], sB = srcs[i + 1];
    float wA = alpha[(size_t)i * 4 + h];
    float wB = alpha[(size_t)(i + 1) * 4 + h];
    float xA[VEC], xB[VEC];
    load_bf<VEC>(xs + (size_t)sA * HC + h * CH + c, xA);
    load_bf<VEC>(xs + (size_t)sB * HC + h * CH + c, xB);
#pragma unroll
    for (int v = 0; v < VEC; ++v) acc[v] += wA * xA[v] + wB * xB[v];
  }
  if (i < end) {
    int sA = srcs[i];
    float wA = alpha[(size_t)i * 4 + h];
    float xA[VEC];
    load_bf<VEC>(xs + (size_t)sA * HC + h * CH + c, xA);
#pragma unroll
    for (int v = 0; v < VEC; ++v) acc[v] += wA * xA[v];
  }
  float r = rden[(size_t)n * 4 + h];
  size_t obase = (size_t)n * HC + h * CH + c;
  float sk[VEC];
  load_bf<VEC>(skip + obase, sk);
#pragma unroll
  for (int v = 0; v < VEC; ++v) {
    float val = acc[v] * r + bias[h * CH + c + v] + sk[v];
    if (RELU) val = fmaxf(val, 0.f);
    if (OUT_BF16) ((ushort*)outv)[obase + v] = f2bf(val);
    else          ((float*)outv)[obase + v] = val;
  }
}

// ---------------- host launch ----------------
extern "C" void kernel_launch(void* const* d_in, const int* in_sizes, int n_in,
                              void* d_out, int out_size, void* d_ws, size_t ws_size,
                              hipStream_t stream) {
  const float* x      = (const float*)d_in[0];
  const int*   ei     = (const int*)d_in[1];
  const float* W_rna  = (const float*)d_in[3];
  const float* b_rna  = (const float*)d_in[4];
  const float* W_prot = (const float*)d_in[5];
  const float* b_prot = (const float*)d_in[6];
  const float* W1s    = (const float*)d_in[7];
  const float* W1d    = (const float*)d_in[8];
  const float* at1s   = (const float*)d_in[9];
  const float* at1d   = (const float*)d_in[10];
  const float* bias1  = (const float*)d_in[11];
  const float* Wl1    = (const float*)d_in[12];
  const float* bl1    = (const float*)d_in[13];
  const float* W2s    = (const float*)d_in[14];
  const float* W2d    = (const float*)d_in[15];
  const float* at2s   = (const float*)d_in[16];
  const float* at2d   = (const float*)d_in[17];
  const float* bias2  = (const float*)d_in[18];
  const float* Wl2    = (const float*)d_in[19];
  const float* bl2    = (const float*)d_in[20];

  const int N = in_sizes[0] / D_IN;   // 40000
  const int E = in_sizes[1] / 2;      // 640000
  const int* srcv = ei;
  const int* dstv = ei + E;

  char* ws = (char*)d_ws;
  size_t o = 0;
  auto carve = [&](size_t bytes) {
    void* p = ws + o;
    o += (bytes + 255) & ~(size_t)255;
    return p;
  };
  int* deg    = (int*)carve((size_t)N * 4);
  int* offp   = (int*)carve((size_t)(N + 1) * 4);
  int* cur    = (int*)carve((size_t)N * 4);
  int* srcs   = (int*)carve((size_t)E * 4);
  float* v1s  = (float*)carve(HDIM * HEADS * 4);
  float* v1d  = (float*)carve(HDIM * HEADS * 4);
  float* v2s  = (float*)carve(HC1 * HEADS * 4);
  float* v2d  = (float*)carve(HC1 * HEADS * 4);
  float* a_s  = (float*)carve((size_t)N * 4 * 4);
  float* a_d  = (float*)carve((size_t)N * 4 * 4);
  float* rden = (float*)carve((size_t)N * 4 * 4);
  float* alpha = (float*)carve((size_t)E * 4 * 4);
  ushort* BTr = (ushort*)carve(64 * 1024 * 2);
  ushort* BTp = (ushort*)carve(64 * 320 * 2);
  ushort* BT1 = (ushort*)carve(512 * 128 * 2);
  ushort* BT2 = (ushort*)carve(256 * 256 * 2);
  float* biasL1 = (float*)carve(512 * 4);
  float* biasL2 = (float*)carve(256 * 4);
  ushort* h0  = (ushort*)carve((size_t)N * HDIM * 2);
  ushort* xs1 = (ushort*)carve((size_t)N * HC1 * 2);
  ushort* z1  = (ushort*)carve((size_t)N * HC1 * 2);
  ushort* h1  = (ushort*)carve((size_t)N * HC1 * 2);
  ushort* xs2 = h0;   // h0 dead after layer-1 gemm + attn_proj1
  ushort* z2  = z1;   // z1 dead after aggregate1
  float* out = (float*)d_out;

  // 1. counting-sort edges by dst
  zero_i32<<<(N + 255) / 256, 256, 0, stream>>>(deg, N);
  hist_kernel<<<(E + 255) / 256, 256, 0, stream>>>(dstv, deg, E);
  scan_kernel<<<1, 1024, 0, stream>>>(deg, offp, cur, N);
  scatter_kernel<<<(E + 255) / 256, 256, 0, stream>>>(srcv, dstv, cur, srcs, E);
  // 2. fold att + weight conversion
  fold_att_kernel<<<8, 256, 0, stream>>>(W1s, W1d, at1s, at1d, W2s, W2d, at2s, at2d,
                                         v1s, v1d, v2s, v2d);
  convert_weights<<<256, 256, 0, stream>>>(W_rna, W_prot, W1s, Wl1, W2s, Wl2,
                                           bias1, bl1, bias2, bl2,
                                           BTr, BTp, BT1, BT2, biasL1, biasL2);
  // 3. embedding -> h0[N,128] bf16
  embed_gemm<<<dim3(2, N / 64), 256, 0, stream>>>(x, BTr, BTp, b_rna, b_prot, h0);
  // 4. layer-1: [xs1|z1] = h0 @ [W1s|Wl1] (+bias), bf16
  layer_gemm<<<dim3(8, N / 64), 256, 0, stream>>>(h0, HDIM, BT1, biasL1, xs1, z1, HC1);
  attn_proj_kernel<<<N / 4, 256, 8 * HDIM * 4, stream>>>(h0, HDIM, v1s, v1d, a_s, a_d, N);
  // 5. layer-1 softmax + aggregate -> h1 = relu(agg + bias1 + z1), bf16
  edge_softmax_kernel<<<N / 16, 256, 0, stream>>>(offp, srcs, a_s, a_d, alpha, rden, N);
  aggregate_kernel<CH1, 4, true, true><<<N / 4, 256, 0, stream>>>(offp, srcs, alpha, rden, xs1,
                                                                  bias1, z1, h1, N);
  // 6. layer-2
  layer_gemm<<<dim3(4, N / 64), 256, 0, stream>>>(h1, HC1, BT2, biasL2, xs2, z2, HC2);
  attn_proj_kernel<<<N / 4, 256, 8 * HC1 * 4, stream>>>(h1, HC1, v2s, v2d, a_s, a_d, N);
  edge_softmax_kernel<<<N / 16, 256, 0, stream>>>(offp, srcs, a_s, a_d, alpha, rden, N);
  aggregate_kernel<CH2, 2, false, false><<<N / 4, 256, 0, stream>>>(offp, srcs, alpha, rden, xs2,
                                                                    bias2, z2, out, N);
}